// Round 18
// baseline (579.620 us; speedup 1.0000x reference)
//
#include <hip/hip_runtime.h>
#include <hip/hip_fp16.h>

#define NN 100000
#define NE 800000
#define DD 128
#define NL 4
#define NG 512
#define NT 10
#define BN_EPS 1e-5f
#define SCAN_B 1024
#define CHUNK 7

typedef __attribute__((ext_vector_type(4))) float f32x4;
typedef __attribute__((ext_vector_type(8))) _Float16 f16x8;

#define ECH 782        // edge chunks of 1024 edges
#define EB8 (ECH * 8)  // sliced edge blocks
#define TB 72          // table blocks
#define AB 12500       // atom-encoder blocks
#define GB0 1563       // gemm-l0 blocks in FAT2
#define CB 3125        // csr_fill blocks in FAT2

__device__ __forceinline__ float atomAddF(float* p, float v) {
  return unsafeAtomicAdd(p, v);
}

// ---------------- FAT1: sliced edge_count ∥ tables ∥ atom_encoder ----------------

__global__ __launch_bounds__(256) void fat1_kernel(
    const int* __restrict__ ei, int* __restrict__ degcnt,
    int* __restrict__ incnt, int* __restrict__ erank,
    const float* __restrict__ W, __half* __restrict__ Wf,
    const int* __restrict__ batch, int* __restrict__ gstart,
    const int* __restrict__ x, const float* __restrict__ atom_emb,
    __half* __restrict__ h) {
  __shared__ int xs[8 * 9];
  const int bid = blockIdx.x;
  const int t = threadIdx.x;
  if (bid < EB8) {
    const int sub = bid & 7;
    const int e4 = (bid >> 3) * 1024 + t * 4;
    if (e4 < NE) {
      int4 s = *reinterpret_cast<const int4*>(&ei[e4]);
      int4 d = *reinterpret_cast<const int4*>(&ei[NE + e4]);
      if (((s.x >> 5) & 7) == sub) atomicAdd(&degcnt[s.x], 1);
      if (((s.y >> 5) & 7) == sub) atomicAdd(&degcnt[s.y], 1);
      if (((s.z >> 5) & 7) == sub) atomicAdd(&degcnt[s.z], 1);
      if (((s.w >> 5) & 7) == sub) atomicAdd(&degcnt[s.w], 1);
      if (((d.x >> 5) & 7) == sub) erank[e4 + 0] = atomicAdd(&incnt[d.x], 1);
      if (((d.y >> 5) & 7) == sub) erank[e4 + 1] = atomicAdd(&incnt[d.y], 1);
      if (((d.z >> 5) & 7) == sub) erank[e4 + 2] = atomicAdd(&incnt[d.z], 1);
      if (((d.w >> 5) & 7) == sub) erank[e4 + 3] = atomicAdd(&incnt[d.w], 1);
    }
    return;
  }
  if (bid < EB8 + TB) {
    const int idx = (bid - EB8) * 256 + t;
    if (idx < NL * 8 * 4 * 64) {  // W -> fragment-ordered fp16
      int lane = idx & 63;
      int c = (idx >> 6) & 3;
      int tt = (idx >> 8) & 7;
      int l = idx >> 11;
      const float* Wl = W + l * DD * DD;
      __half* o = Wf + idx * 8;
      int n = tt * 16 + (lane & 15);
      int k0 = c * 32 + (lane >> 4) * 8;
#pragma unroll
      for (int i = 0; i < 8; ++i) o[i] = (__half)Wl[(k0 + i) * DD + n];
    }
    if (idx <= NG) {
      if (idx == NG) {
        gstart[NG] = NN;
      } else {
        int lo = 0, hi = NN;
        while (lo < hi) {
          int m = (lo + hi) >> 1;
          if (batch[m] < idx) lo = m + 1; else hi = m;
        }
        gstart[idx] = lo;
      }
    }
    return;
  }
  // ---- atom encoder ----
  const int nb = (bid - EB8 - TB) * 8;
  if (t < 72) {
    int gi = nb * 9 + t;
    xs[t] = (gi < NN * 9) ? x[gi] : 0;
  }
  __syncthreads();
  const int n = nb + (t >> 5);
  const int q = t & 31;
  if (n >= NN) return;
  float4 acc = make_float4(0.f, 0.f, 0.f, 0.f);
#pragma unroll
  for (int f = 0; f < 9; ++f) {
    int r = xs[(t >> 5) * 9 + f];
    float4 v = *reinterpret_cast<const float4*>(&atom_emb[(f * 64 + r) * DD + q * 4]);
    acc.x += v.x; acc.y += v.y; acc.z += v.z; acc.w += v.w;
  }
  union { __half2 hh[2]; int2 i2; } u;
  u.hh[0] = __floats2half2_rn(acc.x, acc.y);
  u.hh[1] = __floats2half2_rn(acc.z, acc.w);
  *reinterpret_cast<int2*>(&h[n * DD + q * 4]) = u.i2;
}

// ---------------- CSR scans ----------------

__global__ __launch_bounds__(256) void scan1_kernel(
    const int* __restrict__ in, int* __restrict__ out, int* __restrict__ bsum,
    const int* __restrict__ degcnt, float* __restrict__ degrecip,
    float* __restrict__ dinv, int n) {
  __shared__ int s[256];
  int base = blockIdx.x * SCAN_B + threadIdx.x * 4;
  int v[4] = {0, 0, 0, 0};
  if (base + 3 < n) {
    int4 t = *reinterpret_cast<const int4*>(&in[base]);
    v[0] = t.x; v[1] = t.y; v[2] = t.z; v[3] = t.w;
  } else {
    for (int i = 0; i < 4; ++i) v[i] = (base + i < n) ? in[base + i] : 0;
  }
  for (int i = 0; i < 4; ++i) {
    if (base + i < n) {
      float dv = (float)degcnt[base + i] + 1.f;
      degrecip[base + i] = 1.f / dv;
      dinv[base + i] = rsqrtf(dv);
    }
  }
  int tsum = v[0] + v[1] + v[2] + v[3];
  s[threadIdx.x] = tsum;
  __syncthreads();
  for (int d = 1; d < 256; d <<= 1) {
    int t = (threadIdx.x >= d) ? s[threadIdx.x - d] : 0;
    __syncthreads();
    s[threadIdx.x] += t;
    __syncthreads();
  }
  int run = s[threadIdx.x] - tsum;
  if (threadIdx.x == 255) bsum[blockIdx.x] = s[255];
  for (int i = 0; i < 4; ++i) {
    if (base + i < n) out[base + i] = run;
    run += v[i];
  }
}

__global__ void scan2_kernel(int* bsum, int nb) {
  __shared__ int s[128];
  int v = (threadIdx.x < nb) ? bsum[threadIdx.x] : 0;
  s[threadIdx.x] = v;
  __syncthreads();
  for (int d = 1; d < 128; d <<= 1) {
    int t = (threadIdx.x >= d) ? s[threadIdx.x - d] : 0;
    __syncthreads();
    s[threadIdx.x] += t;
    __syncthreads();
  }
  if (threadIdx.x < nb) bsum[threadIdx.x] = s[threadIdx.x] - v;
}

__global__ __launch_bounds__(256) void scan3_kernel(int* off, const int* bsum,
                                                    int n, int total) {
  int i = blockIdx.x * 256 + threadIdx.x;
  if (i < n) off[i] += bsum[i / SCAN_B];
  if (i == 0) off[n] = total;
}

// ---------------- GEMM body (optional fused BN-finalize from raw sums) -------

__device__ __forceinline__ void gemm_body(
    int blk, int tid, const __half* __restrict__ A, const __half* __restrict__ Wf,
    const float* __restrict__ bias, const float* __restrict__ bnS,
    const float* __restrict__ bnQ, const float* __restrict__ gamma,
    const float* __restrict__ beta, int fuse_bn, __half* __restrict__ hl,
    float* sc_s, float* sh_s) {
  const int wid = tid >> 6, lane = tid & 63;
  const int r0 = blk * 64 + wid * 16;
  const int arow = min(r0 + (lane & 15), NN - 1);
  const int kb = (lane >> 4) * 8;

  if (fuse_bn) {
    if (tid < DD) {
      float mu = bnS[tid] / (float)NN;
      float var = bnQ[tid] / (float)NN - mu * mu;
      float inv = rsqrtf(var + BN_EPS);
      float sc = gamma[tid] * inv;
      sc_s[tid] = sc;
      sh_s[tid] = beta[tid] - mu * sc;
    }
    __syncthreads();
  }

  f16x8 afrag[4];
#pragma unroll
  for (int c = 0; c < 4; ++c) {
    const int k0 = c * 32 + kb;
    f16x8 raw = *reinterpret_cast<const f16x8*>(&A[arow * DD + k0]);
    if (fuse_bn) {
#pragma unroll
      for (int i = 0; i < 8; ++i) {
        float v = fmaxf((float)raw[i] * sc_s[k0 + i] + sh_s[k0 + i], 0.f);
        raw[i] = (_Float16)v;
      }
    }
    afrag[c] = raw;
  }

  f32x4 acc[8];
#pragma unroll
  for (int t = 0; t < 8; ++t) acc[t] = (f32x4){0.f, 0.f, 0.f, 0.f};

  const f16x8* __restrict__ wf = reinterpret_cast<const f16x8*>(Wf);
#pragma unroll
  for (int t = 0; t < 8; ++t) {
#pragma unroll
    for (int c = 0; c < 4; ++c) {
      f16x8 b = wf[(t * 4 + c) * 64 + lane];
      acc[t] = __builtin_amdgcn_mfma_f32_16x16x32_f16(afrag[c], b, acc[t], 0, 0, 0);
    }
  }

  const int colb = lane & 15;
  const int rbase = r0 + (lane >> 4) * 4;
#pragma unroll
  for (int t = 0; t < 8; ++t) {
    float bb = bias[t * 16 + colb];
#pragma unroll
    for (int j = 0; j < 4; ++j) {
      int row = rbase + j;
      if (row < NN) hl[row * DD + t * 16 + colb] = (__half)(acc[t][j] + bb);
    }
  }
}

__global__ __launch_bounds__(256) void fat2_kernel(
    const __half* __restrict__ A, const __half* __restrict__ Wf,
    const float* __restrict__ bias, __half* __restrict__ hl,
    const int* __restrict__ ei, const int* __restrict__ eattr,
    const float* __restrict__ dinv, const int* __restrict__ off,
    const int* __restrict__ erank, int2* __restrict__ edata) {
  const int bid = blockIdx.x;
  if (bid < GB0) {
    gemm_body(bid, threadIdx.x, A, Wf, bias, nullptr, nullptr, nullptr,
              nullptr, 0, hl, nullptr, nullptr);
    return;
  }
  int e = (bid - GB0) * 256 + threadIdx.x;
  if (e >= NE) return;
  int r = ei[e], c = ei[NE + e];
  int pos = off[c] + erank[e];
  float nm = dinv[r] * dinv[c];
  int idx9 = eattr[e * 3] | (eattr[e * 3 + 1] << 3) | (eattr[e * 3 + 2] << 6);
  int2 d;
  d.x = r | (idx9 << 17);
  d.y = __float_as_int(nm);
  edata[pos] = d;
}

__global__ __launch_bounds__(256) void gemm_mfma_kernel(
    const __half* __restrict__ A, const __half* __restrict__ Wf,
    const float* __restrict__ bias, const float* __restrict__ bnS,
    const float* __restrict__ bnQ, const float* __restrict__ gamma,
    const float* __restrict__ beta, __half* __restrict__ hl) {
  __shared__ float sc_s[DD], sh_s[DD];
  gemm_body(blockIdx.x, threadIdx.x, A, Wf, bias, bnS, bnQ, gamma, beta, 1, hl,
            sc_s, sh_s);
}

// ---------------- fused gather + update + BN stats / pool ----------------
// DUAL-STREAM half-waves, CHUNK=7 unrolled, per-stream loop bound.

__device__ __forceinline__ void gather_node(
    int n, const int* __restrict__ off, const int2* __restrict__ edata,
    const __half2* __restrict__ hl2, const float2* bembS, int sl, int p0,
    float4 rt, const float* __restrict__ degrecip, float& v0, float& v1,
    float& v2, float& v3) {
  int k0 = off[n], k1 = off[n + 1];
  int cnt = k1 - k0;
  float a0 = 0.f, a1 = 0.f, a2 = 0.f, a3 = 0.f;
  for (int i = 0; i < cnt; i += 4) {
    int2 e[4];
#pragma unroll
    for (int j = 0; j < 4; ++j) e[j] = edata[min(k0 + i + j, k1 - 1)];
    int2 hv[4];
#pragma unroll
    for (int j = 0; j < 4; ++j)
      hv[j] = *reinterpret_cast<const int2*>(&hl2[(e[j].x & 0x1FFFF) * 64 + p0]);
#pragma unroll
    for (int j = 0; j < 4; ++j) {
      float nm = ((i + j) < cnt) ? __int_as_float(e[j].y) : 0.f;
      int i9 = e[j].x >> 17;
      float2 h01 = __half22float2(*reinterpret_cast<__half2*>(&hv[j].x));
      float2 h23 = __half22float2(*reinterpret_cast<__half2*>(&hv[j].y));
      const float2* t0 = &bembS[(i9 & 7) * 64];
      const float2* t1 = &bembS[(8 + ((i9 >> 3) & 7)) * 64];
      const float2* t2 = &bembS[(16 + ((i9 >> 6) & 7)) * 64];
      float2 b0a = t0[p0], b0b = t0[p0 + 1];
      float2 b1a = t1[p0], b1b = t1[p0 + 1];
      float2 b2a = t2[p0], b2b = t2[p0 + 1];
      a0 += nm * fmaxf(h01.x + b0a.x + b1a.x + b2a.x, 0.f);
      a1 += nm * fmaxf(h01.y + b0a.y + b1a.y + b2a.y, 0.f);
      a2 += nm * fmaxf(h23.x + b0b.x + b1b.x + b2b.x, 0.f);
      a3 += nm * fmaxf(h23.y + b0b.y + b1b.y + b2b.y, 0.f);
    }
  }
  float dr = degrecip[n];
  int2 hs2 = *reinterpret_cast<const int2*>(&hl2[n * 64 + p0]);
  float2 hs01 = __half22float2(*reinterpret_cast<__half2*>(&hs2.x));
  float2 hs23 = __half22float2(*reinterpret_cast<__half2*>(&hs2.y));
  v0 = a0 + fmaxf(hs01.x + rt.x, 0.f) * dr;
  v1 = a1 + fmaxf(hs01.y + rt.y, 0.f) * dr;
  v2 = a2 + fmaxf(hs23.x + rt.z, 0.f) * dr;
  v3 = a3 + fmaxf(hs23.y + rt.w, 0.f) * dr;
}

__global__ __launch_bounds__(256) void gather_update_kernel(
    const int* __restrict__ off, const int2* __restrict__ edata,
    const __half2* __restrict__ hl2, const float* __restrict__ bemb,
    const float* __restrict__ root, const float* __restrict__ degrecip,
    const int* __restrict__ batch, __half2* __restrict__ h2,
    float* __restrict__ hg, float* __restrict__ bn_sum,
    float* __restrict__ bn_sq, int mode) {  // mode 0: h+stats, 1: pool
  __shared__ float2 bembS[24 * 64];
  __shared__ float s0[DD], s1[DD];
  const float2* bemb2 = reinterpret_cast<const float2*>(bemb);
  for (int i = threadIdx.x; i < 24 * 64; i += 256) bembS[i] = bemb2[i];
  if (mode == 0 && threadIdx.x < DD) {
    s0[threadIdx.x] = 0.f;
    s1[threadIdx.x] = 0.f;
  }
  const int sid = threadIdx.x >> 5;
  const int sl = threadIdx.x & 31;
  const int p0 = 2 * sl;
  float4 rt = *reinterpret_cast<const float4*>(&root[4 * sl]);
  float ls[4] = {0, 0, 0, 0}, lq[4] = {0, 0, 0, 0};
  const int wv = blockIdx.x * 8 + sid;
  const int n0 = wv * CHUNK;
  int curg = -1;
  float pg[4] = {0, 0, 0, 0};
  __syncthreads();

#define NODE_POST(n, v0, v1, v2, v3)                                  \
  if (mode == 0) {                                                    \
    int2 o;                                                           \
    *reinterpret_cast<__half2*>(&o.x) = __floats2half2_rn(v0, v1);    \
    *reinterpret_cast<__half2*>(&o.y) = __floats2half2_rn(v2, v3);    \
    *reinterpret_cast<int2*>(&h2[(n)*64 + p0]) = o;                   \
    ls[0] += v0; ls[1] += v1; ls[2] += v2; ls[3] += v3;               \
    lq[0] += v0 * v0; lq[1] += v1 * v1; lq[2] += v2 * v2;             \
    lq[3] += v3 * v3;                                                 \
  } else {                                                            \
    int g = batch[n];                                                 \
    if (g != curg) {                                                  \
      if (curg >= 0) {                                                \
        atomAddF(&hg[curg * DD + 4 * sl + 0], pg[0]);                 \
        atomAddF(&hg[curg * DD + 4 * sl + 1], pg[1]);                 \
        atomAddF(&hg[curg * DD + 4 * sl + 2], pg[2]);                 \
        atomAddF(&hg[curg * DD + 4 * sl + 3], pg[3]);                 \
      }                                                               \
      curg = g;                                                       \
      pg[0] = v0; pg[1] = v1; pg[2] = v2; pg[3] = v3;                 \
    } else {                                                          \
      pg[0] += v0; pg[1] += v1; pg[2] += v2; pg[3] += v3;             \
    }                                                                 \
  }

  if (n0 + CHUNK <= NN) {
#pragma unroll
    for (int ni = 0; ni < CHUNK; ++ni) {
      int n = n0 + ni;
      float v0, v1, v2, v3;
      gather_node(n, off, edata, hl2, bembS, sl, p0, rt, degrecip, v0, v1, v2, v3);
      NODE_POST(n, v0, v1, v2, v3)
    }
  } else {
    for (int n = n0; n < NN; ++n) {
      float v0, v1, v2, v3;
      gather_node(n, off, edata, hl2, bembS, sl, p0, rt, degrecip, v0, v1, v2, v3);
      NODE_POST(n, v0, v1, v2, v3)
    }
  }
#undef NODE_POST

  if (mode == 1) {
    if (curg >= 0) {
#pragma unroll
      for (int j = 0; j < 4; ++j)
        atomAddF(&hg[curg * DD + 4 * sl + j], pg[j]);
    }
    return;
  }
#pragma unroll
  for (int j = 0; j < 4; ++j) {
    atomicAdd(&s0[4 * sl + j], ls[j]);
    atomicAdd(&s1[4 * sl + j], lq[j]);
  }
  __syncthreads();
  if (threadIdx.x < DD) {
    atomAddF(&bn_sum[threadIdx.x], s0[threadIdx.x]);
    atomAddF(&bn_sq[threadIdx.x], s1[threadIdx.x]);
  }
}

// ---------------- MLP on pooled features ----------------

__global__ __launch_bounds__(128) void mlp_kernel(
    const float* __restrict__ hg, const int* __restrict__ gstart,
    const float* __restrict__ W1, const float* __restrict__ b1,
    const float* __restrict__ W2, const float* __restrict__ b2,
    float* __restrict__ out) {
  int g = blockIdx.x, t = threadIdx.x;
  float cnt = fmaxf((float)(gstart[g + 1] - gstart[g]), 1.f);
  __shared__ float row[DD], t1[DD];
  row[t] = fmaxf(hg[g * DD + t] / cnt, 0.f);
  __syncthreads();
  float a1v = b1[t];
  for (int k = 0; k < DD; ++k) a1v = fmaf(row[k], W1[k * DD + t], a1v);
  t1[t] = fmaxf(a1v, 0.f);
  __syncthreads();
  if (t < NT) {
    float a2 = b2[t];
    for (int k = 0; k < DD; ++k) a2 = fmaf(t1[k], W2[k * NT + t], a2);
    out[g * NT + t] = a2;
  }
}

extern "C" void kernel_launch(void* const* d_in, const int* in_sizes, int n_in,
                              void* d_out, int out_size, void* d_ws,
                              size_t ws_size, hipStream_t stream) {
  const int* x = (const int*)d_in[0];
  const int* edge_index = (const int*)d_in[1];
  const int* batch = (const int*)d_in[2];
  const int* edge_attr = (const int*)d_in[3];
  const float* atom_emb = (const float*)d_in[4];
  const float* W = (const float*)d_in[5];
  const float* b = (const float*)d_in[6];
  const float* root = (const float*)d_in[7];
  const float* bond_emb = (const float*)d_in[8];
  const float* gamma = (const float*)d_in[9];
  const float* beta = (const float*)d_in[10];
  const float* W1 = (const float*)d_in[11];
  const float* b1 = (const float*)d_in[12];
  const float* W2 = (const float*)d_in[13];
  const float* b2 = (const float*)d_in[14];
  float* out = (float*)d_out;

  char* ws = (char*)d_ws;
  size_t off_b = 0;
  auto alloc = [&](size_t bytes) {
    char* p = ws + off_b;
    off_b += (bytes + 255) & ~size_t(255);
    return p;
  };
  __half* h = (__half*)alloc(sizeof(__half) * NN * DD);
  __half* hl = (__half*)alloc(sizeof(__half) * NN * DD);
  int2* edata = (int2*)alloc(sizeof(int2) * NE);
  int* erank = (int*)alloc(sizeof(int) * NE);
  float* degrecip = (float*)alloc(sizeof(float) * NN);
  float* dinv = (float*)alloc(sizeof(float) * NN);
  int* off = (int*)alloc(sizeof(int) * (NN + 1));
  int* bsum = (int*)alloc(sizeof(int) * 128);
  int* gstart = (int*)alloc(sizeof(int) * (NG + 1));
  __half* Wf = (__half*)alloc(sizeof(__half) * NL * DD * DD);
  // ---- contiguous zero region ----
  char* zstart = ws + off_b;
  int* degcnt = (int*)alloc(sizeof(int) * NN);
  int* incnt = (int*)alloc(sizeof(int) * NN);
  float* hg = (float*)alloc(sizeof(float) * NG * DD);
  float* bnS = (float*)alloc(sizeof(float) * NL * DD);
  float* bnQ = (float*)alloc(sizeof(float) * NL * DD);
  size_t zbytes = (ws + off_b) - zstart;

  hipMemsetAsync(zstart, 0, zbytes, stream);

  fat1_kernel<<<EB8 + TB + AB, 256, 0, stream>>>(
      edge_index, degcnt, incnt, erank, W, Wf, batch, gstart, x, atom_emb, h);

  const int nb = (NN + SCAN_B - 1) / SCAN_B;  // 98
  scan1_kernel<<<nb, 256, 0, stream>>>(incnt, off, bsum, degcnt, degrecip,
                                       dinv, NN);
  scan2_kernel<<<1, 128, 0, stream>>>(bsum, nb);
  scan3_kernel<<<(NN + 255) / 256, 256, 0, stream>>>(off, bsum, NN, NE);

  // FAT2: gemm layer-0 ∥ csr_fill
  fat2_kernel<<<GB0 + CB, 256, 0, stream>>>(h, Wf, b, hl, edge_index,
                                            edge_attr, dinv, off, erank, edata);

  const int GB = (NN + 8 * CHUNK - 1) / (8 * CHUNK);  // 1786 blocks
  for (int l = 0; l < NL; ++l) {
    if (l > 0) {
      gemm_mfma_kernel<<<(NN + 63) / 64, 256, 0, stream>>>(
          h, Wf + l * DD * DD, b + l * DD, bnS + (l - 1) * DD,
          bnQ + (l - 1) * DD, gamma + (l - 1) * DD, beta + (l - 1) * DD, hl);
    }
    int mode = (l < NL - 1) ? 0 : 1;
    gather_update_kernel<<<GB, 256, 0, stream>>>(
        off, edata, (const __half2*)hl, bond_emb + l * 3 * 8 * DD,
        root + l * DD, degrecip, batch, (__half2*)h, hg, bnS + l * DD,
        bnQ + l * DD, mode);
  }

  mlp_kernel<<<NG, DD, 0, stream>>>(hg, gstart, W1, b1, W2, b2, out);
}

// Round 19
// 539.897 us; speedup vs baseline: 1.0736x; 1.0736x over previous
//
#include <hip/hip_runtime.h>
#include <hip/hip_fp16.h>

#define NN 100000
#define NE 800000
#define DD 128
#define NL 4
#define NG 512
#define NT 10
#define BN_EPS 1e-5f
#define SCAN_B 1024
#define CHUNK 7

typedef __attribute__((ext_vector_type(4))) float f32x4;
typedef __attribute__((ext_vector_type(8))) _Float16 f16x8;

#define ECH 782        // edge chunks of 1024 edges
#define EB8 (ECH * 8)  // sliced edge blocks
#define TB 72          // table blocks
#define AB 12500       // atom-encoder blocks
#define GB0 1563       // gemm-l0 blocks in FAT2
#define CB 3125        // csr_fill blocks in FAT2

__device__ __forceinline__ float atomAddF(float* p, float v) {
  return unsafeAtomicAdd(p, v);
}

// ---------------- FAT1: sliced edge_count ∥ tables ∥ atom_encoder ----------------

__global__ __launch_bounds__(256) void fat1_kernel(
    const int* __restrict__ ei, int* __restrict__ degcnt,
    int* __restrict__ incnt, int* __restrict__ erank,
    const float* __restrict__ W, __half* __restrict__ Wf,
    const int* __restrict__ batch, int* __restrict__ gstart,
    const int* __restrict__ x, const float* __restrict__ atom_emb,
    __half* __restrict__ h) {
  __shared__ int xs[8 * 9];
  const int bid = blockIdx.x;
  const int t = threadIdx.x;
  if (bid < EB8) {
    const int sub = bid & 7;
    const int e4 = (bid >> 3) * 1024 + t * 4;
    if (e4 < NE) {
      int4 s = *reinterpret_cast<const int4*>(&ei[e4]);
      int4 d = *reinterpret_cast<const int4*>(&ei[NE + e4]);
      if (((s.x >> 5) & 7) == sub) atomicAdd(&degcnt[s.x], 1);
      if (((s.y >> 5) & 7) == sub) atomicAdd(&degcnt[s.y], 1);
      if (((s.z >> 5) & 7) == sub) atomicAdd(&degcnt[s.z], 1);
      if (((s.w >> 5) & 7) == sub) atomicAdd(&degcnt[s.w], 1);
      if (((d.x >> 5) & 7) == sub) erank[e4 + 0] = atomicAdd(&incnt[d.x], 1);
      if (((d.y >> 5) & 7) == sub) erank[e4 + 1] = atomicAdd(&incnt[d.y], 1);
      if (((d.z >> 5) & 7) == sub) erank[e4 + 2] = atomicAdd(&incnt[d.z], 1);
      if (((d.w >> 5) & 7) == sub) erank[e4 + 3] = atomicAdd(&incnt[d.w], 1);
    }
    return;
  }
  if (bid < EB8 + TB) {
    const int idx = (bid - EB8) * 256 + t;
    if (idx < NL * 8 * 4 * 64) {  // W -> fragment-ordered fp16
      int lane = idx & 63;
      int c = (idx >> 6) & 3;
      int tt = (idx >> 8) & 7;
      int l = idx >> 11;
      const float* Wl = W + l * DD * DD;
      __half* o = Wf + idx * 8;
      int n = tt * 16 + (lane & 15);
      int k0 = c * 32 + (lane >> 4) * 8;
#pragma unroll
      for (int i = 0; i < 8; ++i) o[i] = (__half)Wl[(k0 + i) * DD + n];
    }
    if (idx <= NG) {
      if (idx == NG) {
        gstart[NG] = NN;
      } else {
        int lo = 0, hi = NN;
        while (lo < hi) {
          int m = (lo + hi) >> 1;
          if (batch[m] < idx) lo = m + 1; else hi = m;
        }
        gstart[idx] = lo;
      }
    }
    return;
  }
  // ---- atom encoder ----
  const int nb = (bid - EB8 - TB) * 8;
  if (t < 72) {
    int gi = nb * 9 + t;
    xs[t] = (gi < NN * 9) ? x[gi] : 0;
  }
  __syncthreads();
  const int n = nb + (t >> 5);
  const int q = t & 31;
  if (n >= NN) return;
  float4 acc = make_float4(0.f, 0.f, 0.f, 0.f);
#pragma unroll
  for (int f = 0; f < 9; ++f) {
    int r = xs[(t >> 5) * 9 + f];
    float4 v = *reinterpret_cast<const float4*>(&atom_emb[(f * 64 + r) * DD + q * 4]);
    acc.x += v.x; acc.y += v.y; acc.z += v.z; acc.w += v.w;
  }
  union { __half2 hh[2]; int2 i2; } u;
  u.hh[0] = __floats2half2_rn(acc.x, acc.y);
  u.hh[1] = __floats2half2_rn(acc.z, acc.w);
  *reinterpret_cast<int2*>(&h[n * DD + q * 4]) = u.i2;
}

// ---------------- CSR scans ----------------

__global__ __launch_bounds__(256) void scan1_kernel(
    const int* __restrict__ in, int* __restrict__ out, int* __restrict__ bsum,
    const int* __restrict__ degcnt, float* __restrict__ degrecip,
    float* __restrict__ dinv, int n) {
  __shared__ int s[256];
  int base = blockIdx.x * SCAN_B + threadIdx.x * 4;
  int v[4] = {0, 0, 0, 0};
  if (base + 3 < n) {
    int4 t = *reinterpret_cast<const int4*>(&in[base]);
    v[0] = t.x; v[1] = t.y; v[2] = t.z; v[3] = t.w;
  } else {
    for (int i = 0; i < 4; ++i) v[i] = (base + i < n) ? in[base + i] : 0;
  }
  for (int i = 0; i < 4; ++i) {
    if (base + i < n) {
      float dv = (float)degcnt[base + i] + 1.f;
      degrecip[base + i] = 1.f / dv;
      dinv[base + i] = rsqrtf(dv);
    }
  }
  int tsum = v[0] + v[1] + v[2] + v[3];
  s[threadIdx.x] = tsum;
  __syncthreads();
  for (int d = 1; d < 256; d <<= 1) {
    int t = (threadIdx.x >= d) ? s[threadIdx.x - d] : 0;
    __syncthreads();
    s[threadIdx.x] += t;
    __syncthreads();
  }
  int run = s[threadIdx.x] - tsum;
  if (threadIdx.x == 255) bsum[blockIdx.x] = s[255];
  for (int i = 0; i < 4; ++i) {
    if (base + i < n) out[base + i] = run;
    run += v[i];
  }
}

__global__ void scan2_kernel(int* bsum, int nb) {
  __shared__ int s[128];
  int v = (threadIdx.x < nb) ? bsum[threadIdx.x] : 0;
  s[threadIdx.x] = v;
  __syncthreads();
  for (int d = 1; d < 128; d <<= 1) {
    int t = (threadIdx.x >= d) ? s[threadIdx.x - d] : 0;
    __syncthreads();
    s[threadIdx.x] += t;
    __syncthreads();
  }
  if (threadIdx.x < nb) bsum[threadIdx.x] = s[threadIdx.x] - v;
}

__global__ __launch_bounds__(256) void scan3_kernel(int* off, const int* bsum,
                                                    int n, int total) {
  int i = blockIdx.x * 256 + threadIdx.x;
  if (i < n) off[i] += bsum[i / SCAN_B];
  if (i == 0) off[n] = total;
}

// ---------------- GEMM body (optional fused BN-finalize from raw sums) -------

__device__ __forceinline__ void gemm_body(
    int blk, int tid, const __half* __restrict__ A, const __half* __restrict__ Wf,
    const float* __restrict__ bias, const float* __restrict__ bnS,
    const float* __restrict__ bnQ, const float* __restrict__ gamma,
    const float* __restrict__ beta, int fuse_bn, __half* __restrict__ hl,
    float* sc_s, float* sh_s) {
  const int wid = tid >> 6, lane = tid & 63;
  const int r0 = blk * 64 + wid * 16;
  const int arow = min(r0 + (lane & 15), NN - 1);
  const int kb = (lane >> 4) * 8;

  if (fuse_bn) {
    if (tid < DD) {
      float mu = bnS[tid] / (float)NN;
      float var = bnQ[tid] / (float)NN - mu * mu;
      float inv = rsqrtf(var + BN_EPS);
      float sc = gamma[tid] * inv;
      sc_s[tid] = sc;
      sh_s[tid] = beta[tid] - mu * sc;
    }
    __syncthreads();
  }

  f16x8 afrag[4];
#pragma unroll
  for (int c = 0; c < 4; ++c) {
    const int k0 = c * 32 + kb;
    f16x8 raw = *reinterpret_cast<const f16x8*>(&A[arow * DD + k0]);
    if (fuse_bn) {
#pragma unroll
      for (int i = 0; i < 8; ++i) {
        float v = fmaxf((float)raw[i] * sc_s[k0 + i] + sh_s[k0 + i], 0.f);
        raw[i] = (_Float16)v;
      }
    }
    afrag[c] = raw;
  }

  f32x4 acc[8];
#pragma unroll
  for (int t = 0; t < 8; ++t) acc[t] = (f32x4){0.f, 0.f, 0.f, 0.f};

  const f16x8* __restrict__ wf = reinterpret_cast<const f16x8*>(Wf);
#pragma unroll
  for (int t = 0; t < 8; ++t) {
#pragma unroll
    for (int c = 0; c < 4; ++c) {
      f16x8 b = wf[(t * 4 + c) * 64 + lane];
      acc[t] = __builtin_amdgcn_mfma_f32_16x16x32_f16(afrag[c], b, acc[t], 0, 0, 0);
    }
  }

  const int colb = lane & 15;
  const int rbase = r0 + (lane >> 4) * 4;
#pragma unroll
  for (int t = 0; t < 8; ++t) {
    float bb = bias[t * 16 + colb];
#pragma unroll
    for (int j = 0; j < 4; ++j) {
      int row = rbase + j;
      if (row < NN) hl[row * DD + t * 16 + colb] = (__half)(acc[t][j] + bb);
    }
  }
}

__global__ __launch_bounds__(256) void fat2_kernel(
    const __half* __restrict__ A, const __half* __restrict__ Wf,
    const float* __restrict__ bias, __half* __restrict__ hl,
    const int* __restrict__ ei, const int* __restrict__ eattr,
    const float* __restrict__ dinv, const int* __restrict__ off,
    const int* __restrict__ erank, int2* __restrict__ edata) {
  const int bid = blockIdx.x;
  if (bid < GB0) {
    gemm_body(bid, threadIdx.x, A, Wf, bias, nullptr, nullptr, nullptr,
              nullptr, 0, hl, nullptr, nullptr);
    return;
  }
  int e = (bid - GB0) * 256 + threadIdx.x;
  if (e >= NE) return;
  int r = ei[e], c = ei[NE + e];
  int pos = off[c] + erank[e];
  float nm = dinv[r] * dinv[c];
  int idx9 = eattr[e * 3] | (eattr[e * 3 + 1] << 3) | (eattr[e * 3 + 2] << 6);
  int2 d;
  d.x = r | (idx9 << 17);
  d.y = __float_as_int(nm);
  edata[pos] = d;
}

__global__ __launch_bounds__(256) void gemm_mfma_kernel(
    const __half* __restrict__ A, const __half* __restrict__ Wf,
    const float* __restrict__ bias, const float* __restrict__ bnS,
    const float* __restrict__ bnQ, const float* __restrict__ gamma,
    const float* __restrict__ beta, __half* __restrict__ hl) {
  __shared__ float sc_s[DD], sh_s[DD];
  gemm_body(blockIdx.x, threadIdx.x, A, Wf, bias, bnS, bnQ, gamma, beta, 1, hl,
            sc_s, sh_s);
}

// ---------------- fused gather + update + BN stats / pool ----------------
// R17-proven: DUAL-STREAM half-waves, CHUNK=7 runtime loop, fp32 LDS table.

__global__ __launch_bounds__(256) void gather_update_kernel(
    const int* __restrict__ off, const int2* __restrict__ edata,
    const __half2* __restrict__ hl2, const float* __restrict__ bemb,
    const float* __restrict__ root, const float* __restrict__ degrecip,
    const int* __restrict__ batch, __half2* __restrict__ h2,
    float* __restrict__ hg, float* __restrict__ bn_sum,
    float* __restrict__ bn_sq, int mode) {  // mode 0: h+stats, 1: pool
  __shared__ float2 bembS[24 * 64];
  __shared__ float s0[DD], s1[DD];
  const float2* bemb2 = reinterpret_cast<const float2*>(bemb);
  for (int i = threadIdx.x; i < 24 * 64; i += 256) bembS[i] = bemb2[i];
  if (mode == 0 && threadIdx.x < DD) {
    s0[threadIdx.x] = 0.f;
    s1[threadIdx.x] = 0.f;
  }
  const int sid = threadIdx.x >> 5;
  const int sl = threadIdx.x & 31;
  const int p0 = 2 * sl;
  float4 rt = *reinterpret_cast<const float4*>(&root[4 * sl]);
  float ls[4] = {0, 0, 0, 0}, lq[4] = {0, 0, 0, 0};
  const int wv = blockIdx.x * 8 + sid;
  const int n0 = wv * CHUNK;
  const int n1 = min(n0 + CHUNK, NN);
  int curg = -1;
  float pg[4] = {0, 0, 0, 0};
  __syncthreads();
  for (int n = n0; n < n1; ++n) {
    int k0 = off[n], k1 = off[n + 1];
    int cnt = k1 - k0;
    int mx = max(cnt, __shfl_xor(cnt, 32));
    float a0 = 0.f, a1 = 0.f, a2 = 0.f, a3 = 0.f;
    for (int i = 0; i < mx; i += 4) {
      int2 e[4];
#pragma unroll
      for (int j = 0; j < 4; ++j) e[j] = edata[min(k0 + i + j, NE - 1)];
      int2 hv[4];
#pragma unroll
      for (int j = 0; j < 4; ++j)
        hv[j] = *reinterpret_cast<const int2*>(&hl2[(e[j].x & 0x1FFFF) * 64 + p0]);
#pragma unroll
      for (int j = 0; j < 4; ++j) {
        float nm = ((i + j) < cnt) ? __int_as_float(e[j].y) : 0.f;
        int i9 = e[j].x >> 17;
        float2 h01 = __half22float2(*reinterpret_cast<__half2*>(&hv[j].x));
        float2 h23 = __half22float2(*reinterpret_cast<__half2*>(&hv[j].y));
        const float2* t0 = &bembS[(i9 & 7) * 64];
        const float2* t1 = &bembS[(8 + ((i9 >> 3) & 7)) * 64];
        const float2* t2 = &bembS[(16 + ((i9 >> 6) & 7)) * 64];
        float2 b0a = t0[p0], b0b = t0[p0 + 1];
        float2 b1a = t1[p0], b1b = t1[p0 + 1];
        float2 b2a = t2[p0], b2b = t2[p0 + 1];
        a0 += nm * fmaxf(h01.x + b0a.x + b1a.x + b2a.x, 0.f);
        a1 += nm * fmaxf(h01.y + b0a.y + b1a.y + b2a.y, 0.f);
        a2 += nm * fmaxf(h23.x + b0b.x + b1b.x + b2b.x, 0.f);
        a3 += nm * fmaxf(h23.y + b0b.y + b1b.y + b2b.y, 0.f);
      }
    }
    float dr = degrecip[n];
    int2 hs2 = *reinterpret_cast<const int2*>(&hl2[n * 64 + p0]);
    float2 hs01 = __half22float2(*reinterpret_cast<__half2*>(&hs2.x));
    float2 hs23 = __half22float2(*reinterpret_cast<__half2*>(&hs2.y));
    float v0 = a0 + fmaxf(hs01.x + rt.x, 0.f) * dr;
    float v1 = a1 + fmaxf(hs01.y + rt.y, 0.f) * dr;
    float v2 = a2 + fmaxf(hs23.x + rt.z, 0.f) * dr;
    float v3 = a3 + fmaxf(hs23.y + rt.w, 0.f) * dr;
    if (mode == 0) {
      int2 o;
      *reinterpret_cast<__half2*>(&o.x) = __floats2half2_rn(v0, v1);
      *reinterpret_cast<__half2*>(&o.y) = __floats2half2_rn(v2, v3);
      *reinterpret_cast<int2*>(&h2[n * 64 + p0]) = o;
      ls[0] += v0; ls[1] += v1; ls[2] += v2; ls[3] += v3;
      lq[0] += v0 * v0; lq[1] += v1 * v1; lq[2] += v2 * v2; lq[3] += v3 * v3;
    } else {
      int g = batch[n];
      if (g != curg) {
        if (curg >= 0) {
#pragma unroll
          for (int j = 0; j < 4; ++j)
            atomAddF(&hg[curg * DD + 4 * sl + j], pg[j]);
        }
        curg = g;
        pg[0] = v0; pg[1] = v1; pg[2] = v2; pg[3] = v3;
      } else {
        pg[0] += v0; pg[1] += v1; pg[2] += v2; pg[3] += v3;
      }
    }
  }
  if (mode == 1) {
    if (curg >= 0) {
#pragma unroll
      for (int j = 0; j < 4; ++j)
        atomAddF(&hg[curg * DD + 4 * sl + j], pg[j]);
    }
    return;
  }
#pragma unroll
  for (int j = 0; j < 4; ++j) {
    atomicAdd(&s0[4 * sl + j], ls[j]);
    atomicAdd(&s1[4 * sl + j], lq[j]);
  }
  __syncthreads();
  if (threadIdx.x < DD) {
    atomAddF(&bn_sum[threadIdx.x], s0[threadIdx.x]);
    atomAddF(&bn_sq[threadIdx.x], s1[threadIdx.x]);
  }
}

// ---------------- MLP on pooled features ----------------

__global__ __launch_bounds__(128) void mlp_kernel(
    const float* __restrict__ hg, const int* __restrict__ gstart,
    const float* __restrict__ W1, const float* __restrict__ b1,
    const float* __restrict__ W2, const float* __restrict__ b2,
    float* __restrict__ out) {
  int g = blockIdx.x, t = threadIdx.x;
  float cnt = fmaxf((float)(gstart[g + 1] - gstart[g]), 1.f);
  __shared__ float row[DD], t1[DD];
  row[t] = fmaxf(hg[g * DD + t] / cnt, 0.f);
  __syncthreads();
  float a1v = b1[t];
  for (int k = 0; k < DD; ++k) a1v = fmaf(row[k], W1[k * DD + t], a1v);
  t1[t] = fmaxf(a1v, 0.f);
  __syncthreads();
  if (t < NT) {
    float a2 = b2[t];
    for (int k = 0; k < DD; ++k) a2 = fmaf(t1[k], W2[k * NT + t], a2);
    out[g * NT + t] = a2;
  }
}

extern "C" void kernel_launch(void* const* d_in, const int* in_sizes, int n_in,
                              void* d_out, int out_size, void* d_ws,
                              size_t ws_size, hipStream_t stream) {
  const int* x = (const int*)d_in[0];
  const int* edge_index = (const int*)d_in[1];
  const int* batch = (const int*)d_in[2];
  const int* edge_attr = (const int*)d_in[3];
  const float* atom_emb = (const float*)d_in[4];
  const float* W = (const float*)d_in[5];
  const float* b = (const float*)d_in[6];
  const float* root = (const float*)d_in[7];
  const float* bond_emb = (const float*)d_in[8];
  const float* gamma = (const float*)d_in[9];
  const float* beta = (const float*)d_in[10];
  const float* W1 = (const float*)d_in[11];
  const float* b1 = (const float*)d_in[12];
  const float* W2 = (const float*)d_in[13];
  const float* b2 = (const float*)d_in[14];
  float* out = (float*)d_out;

  char* ws = (char*)d_ws;
  size_t off_b = 0;
  auto alloc = [&](size_t bytes) {
    char* p = ws + off_b;
    off_b += (bytes + 255) & ~size_t(255);
    return p;
  };
  __half* h = (__half*)alloc(sizeof(__half) * NN * DD);
  __half* hl = (__half*)alloc(sizeof(__half) * NN * DD);
  int2* edata = (int2*)alloc(sizeof(int2) * NE);
  int* erank = (int*)alloc(sizeof(int) * NE);
  float* degrecip = (float*)alloc(sizeof(float) * NN);
  float* dinv = (float*)alloc(sizeof(float) * NN);
  int* off = (int*)alloc(sizeof(int) * (NN + 1));
  int* bsum = (int*)alloc(sizeof(int) * 128);
  int* gstart = (int*)alloc(sizeof(int) * (NG + 1));
  __half* Wf = (__half*)alloc(sizeof(__half) * NL * DD * DD);
  // ---- contiguous zero region ----
  char* zstart = ws + off_b;
  int* degcnt = (int*)alloc(sizeof(int) * NN);
  int* incnt = (int*)alloc(sizeof(int) * NN);
  float* hg = (float*)alloc(sizeof(float) * NG * DD);
  float* bnS = (float*)alloc(sizeof(float) * NL * DD);
  float* bnQ = (float*)alloc(sizeof(float) * NL * DD);
  size_t zbytes = (ws + off_b) - zstart;

  hipMemsetAsync(zstart, 0, zbytes, stream);

  fat1_kernel<<<EB8 + TB + AB, 256, 0, stream>>>(
      edge_index, degcnt, incnt, erank, W, Wf, batch, gstart, x, atom_emb, h);

  const int nb = (NN + SCAN_B - 1) / SCAN_B;  // 98
  scan1_kernel<<<nb, 256, 0, stream>>>(incnt, off, bsum, degcnt, degrecip,
                                       dinv, NN);
  scan2_kernel<<<1, 128, 0, stream>>>(bsum, nb);
  scan3_kernel<<<(NN + 255) / 256, 256, 0, stream>>>(off, bsum, NN, NE);

  // FAT2: gemm layer-0 ∥ csr_fill
  fat2_kernel<<<GB0 + CB, 256, 0, stream>>>(h, Wf, b, hl, edge_index,
                                            edge_attr, dinv, off, erank, edata);

  const int GB = (NN + 8 * CHUNK - 1) / (8 * CHUNK);  // 1786 blocks
  for (int l = 0; l < NL; ++l) {
    if (l > 0) {
      gemm_mfma_kernel<<<(NN + 63) / 64, 256, 0, stream>>>(
          h, Wf + l * DD * DD, b + l * DD, bnS + (l - 1) * DD,
          bnQ + (l - 1) * DD, gamma + (l - 1) * DD, beta + (l - 1) * DD, hl);
    }
    int mode = (l < NL - 1) ? 0 : 1;
    gather_update_kernel<<<GB, 256, 0, stream>>>(
        off, edata, (const __half2*)hl, bond_emb + l * 3 * 8 * DD,
        root + l * DD, degrecip, batch, (__half2*)h, hg, bnS + l * DD,
        bnQ + l * DD, mode);
  }

  mlp_kernel<<<NG, DD, 0, stream>>>(hg, gstart, W1, b1, W2, b2, out);
}